// Round 3
// baseline (4227.207 us; speedup 1.0000x reference)
//
#include <hip/hip_runtime.h>
#include <hip/hip_bf16.h>
#include <math.h>

// ViT-B/16 forward, B=32. All heavy matmuls via bf16 MFMA 16x16x32 (fp32 accum).
// R5: depth-3 software pipeline with counted vmcnt (T4). 4 LDS buffers (64 KB);
//     steady phase waits vmcnt(4) so 2 stages stay in flight across barriers --
//     HBM latency (~900cy, tiles miss the 4MB XCD L2) amortized over 3 phases
//     instead of exposed every phase. 8-wave 128x128 structure from R4 kept.

using bf16 = __hip_bfloat16;
typedef __attribute__((ext_vector_type(8))) short short8;   // 8 x bf16 MFMA operand
typedef __attribute__((ext_vector_type(4))) float floatx4;  // MFMA accumulator

__device__ __forceinline__ void async_copy16(const bf16* g, bf16* l) {
    __builtin_amdgcn_global_load_lds(
        (const __attribute__((address_space(1))) void*)g,
        (__attribute__((address_space(3))) void*)l, 16, 0, 0);
}

// ---------------------------------------------------------------------------
// Generic NT GEMM: C[m,n] = epi( scale * sum_k A[m,k]*B[n,k] + bias[n] (+resid) )
// A bf16 [lda], B bf16 [ldb] (row n holds B^T row = weights [N][K]).
// 128x128 tile, 512 threads = 8 waves in a 4x2 grid; each wave owns a 32x64
// output sub-tile = 2x4 frags of 16x16x32 MFMA (8 MFMA / K-tile / wave).
// Staging: per K-tile each operand tile is 128 rows x 32 bf16 = 8 KB = 8 chunks
// of 1 KB; wave w stages A-chunk w and B-chunk w via global_load_lds.
// Pipeline (depth 3, 4 buffers):
//   prologue: stage(0), stage(1), stage(2)            [6 loads in flight]
//   phase kt: s_waitcnt vmcnt(4)   -> my stage(kt) landed (2 newer in flight)
//             s_barrier            -> everyone's stage(kt) landed; buffer
//                                     (kt+3)&3 fully consumed (compute(kt-1)
//                                     preceded this barrier on all waves)
//             stage(kt+3)          -> overwrites (kt-1)&3, stays in flight
//             compute(kt)
//   tail: peeled with vmcnt(4)/vmcnt(2)/vmcnt(0) literal immediates.
// Two-level batching: bz = bo*batchInner + bi.
// ---------------------------------------------------------------------------
template<int OUT_BF16, int ACT_GELU, int RESID>
__global__ __launch_bounds__(512, 4) void gemm_nt(
    const bf16* __restrict__ A, const bf16* __restrict__ B, void* __restrict__ Cout,
    const float* __restrict__ resid, const float* __restrict__ bias, float scale,
    int M, int N, int K, int lda, int ldb, int ldc,
    int batchInner, long sAi, long sAo, long sBi, long sBo, long sCi, long sCo)
{
    __shared__ __align__(16) bf16 As[4][128 * 32];
    __shared__ __align__(16) bf16 Bs[4][128 * 32];

    const int bz = blockIdx.z;
    const int bi = bz % batchInner, bo = bz / batchInner;
    const bf16* Ab = A + (long)bi * sAi + (long)bo * sAo;
    const bf16* Bb = B + (long)bi * sBi + (long)bo * sBo;
    const long coff = (long)bi * sCi + (long)bo * sCo;

    // Bijective XCD-aware swizzle (m204): contiguous tile runs per XCD L2.
    const int nbx = gridDim.x;
    const int nwg = nbx * gridDim.y;
    const int orig = blockIdx.y * nbx + blockIdx.x;
    const int q8 = nwg >> 3, r8 = nwg & 7;
    const int xcd = orig & 7, sidx = orig >> 3;
    const int wg = (xcd < r8 ? xcd * (q8 + 1) : r8 * (q8 + 1) + (xcd - r8) * q8) + sidx;
    const int m0 = (wg / nbx) << 7;
    const int n0 = (wg % nbx) << 7;

    const int tid  = threadIdx.x;
    const int lane = tid & 63;
    const int wave = tid >> 6;           // 0..7
    const int wrow = (wave >> 1) << 5;   // 0,32,64,96
    const int wcol = (wave & 1) << 6;    // 0 or 64
    const int quad = lane >> 4;
    const int l16  = lane & 15;

    floatx4 acc[2][4];
#pragma unroll
    for (int i = 0; i < 2; i++)
#pragma unroll
        for (int j = 0; j < 4; j++) acc[i][j] = (floatx4)0.0f;

    // Async-staging map: chunk w covers rows w*16..w*16+15 (1 KB at base+w*512).
    const int rIn = lane >> 2;            // row within chunk 0..15
    const int seg = (lane & 3) << 3;      // element offset 0,8,16,24
    const int rA = wave * 16 + rIn;
    const long aOff = (long)min(m0 + rA, M - 1) * lda + seg;
    const long bOff = (long)min(n0 + rA, N - 1) * ldb + seg;

    auto stage = [&](int buf, int kt) {
        const long kb = (long)kt << 5;
        async_copy16(Ab + aOff + kb, &As[buf][wave * 512]);
        async_copy16(Bb + bOff + kb, &Bs[buf][wave * 512]);
    };

    auto compute = [&](const bf16* __restrict__ Asb, const bf16* __restrict__ Bsb) {
        short8 af[2], bfr[4];
#pragma unroll
        for (int i = 0; i < 2; i++)
            af[i]  = *(const short8*)(&Asb[(wrow + i * 16 + l16) * 32 + quad * 8]);
#pragma unroll
        for (int j = 0; j < 4; j++)
            bfr[j] = *(const short8*)(&Bsb[(wcol + j * 16 + l16) * 32 + quad * 8]);
#pragma unroll
        for (int i = 0; i < 2; i++)
#pragma unroll
            for (int j = 0; j < 4; j++)
                acc[i][j] = __builtin_amdgcn_mfma_f32_16x16x32_bf16(
                    af[i], bfr[j], acc[i][j], 0, 0, 0);
    };

    const int kTiles = K >> 5;   // K is always a multiple of 32 here; kTiles >= 2
    const int pre = kTiles < 3 ? kTiles : 3;
    for (int t = 0; t < pre; ++t) stage(t, t);

    int kt = 0;
    for (; kt < kTiles - 3; ++kt) {
        asm volatile("s_waitcnt vmcnt(4)" ::: "memory");
        __builtin_amdgcn_s_barrier();
        asm volatile("" ::: "memory");
        stage((kt + 3) & 3, kt + 3);
        compute(As[kt & 3], Bs[kt & 3]);
    }
    if (kTiles - kt >= 3) {            // 6 loads in flight -> stage(kt) done at 4
        asm volatile("s_waitcnt vmcnt(4)" ::: "memory");
        __builtin_amdgcn_s_barrier();
        asm volatile("" ::: "memory");
        compute(As[kt & 3], Bs[kt & 3]); ++kt;
    }
    if (kTiles - kt >= 2) {            // 4 loads in flight -> stage(kt) done at 2
        asm volatile("s_waitcnt vmcnt(2)" ::: "memory");
        __builtin_amdgcn_s_barrier();
        asm volatile("" ::: "memory");
        compute(As[kt & 3], Bs[kt & 3]); ++kt;
    }
    asm volatile("s_waitcnt vmcnt(0)" ::: "memory");
    __builtin_amdgcn_s_barrier();
    asm volatile("" ::: "memory");
    compute(As[kt & 3], Bs[kt & 3]);

    // Epilogue. C/D frag: col = lane&15, row = quad*4 + r.
#pragma unroll
    for (int i = 0; i < 2; i++) {
        const int rbase = m0 + wrow + i * 16 + quad * 4;
#pragma unroll
        for (int j = 0; j < 4; j++) {
            const int col = n0 + wcol + j * 16 + l16;
            if (col >= N) continue;
            const float bval = bias ? bias[col] : 0.0f;
#pragma unroll
            for (int r = 0; r < 4; r++) {
                const int row = rbase + r;
                if (row >= M) continue;
                const long idx = coff + (long)row * ldc + col;
                float v = acc[i][j][r] * scale + bval;
                if (RESID)    v += resid[idx];
                if (ACT_GELU) v = 0.5f * v * (1.0f + erff(v * 0.70710678118654752f));
                if (OUT_BF16) ((bf16*)Cout)[idx] = __float2bfloat16(v);
                else          ((float*)Cout)[idx] = v;
            }
        }
    }
}

// ---------------------------------------------------------------------------
// Weight repack: fp32 src [K][N] (row k) -> bf16 dst [N][K] (row n). 32x32 LDS tiles.
// ---------------------------------------------------------------------------
__global__ __launch_bounds__(256) void transpose_cvt(
    const float* __restrict__ src, bf16* __restrict__ dst, int K, int N,
    int srcLd, int dstLd, int batchInner, long sSi, long sSo, long sDi, long sDo)
{
    __shared__ float t[32][33];
    const int bz = blockIdx.z;
    const int bi = bz % batchInner, bo = bz / batchInner;
    const float* S = src + (long)bi * sSi + (long)bo * sSo;
    bf16* D = dst + (long)bi * sDi + (long)bo * sDo;
    const int k0 = blockIdx.y << 5, n0 = blockIdx.x << 5;
    const int tx = threadIdx.x & 31, ty = threadIdx.x >> 5;   // 32 x 8
#pragma unroll
    for (int i = 0; i < 32; i += 8) {
        int k = k0 + ty + i, n = n0 + tx;
        if (k < K && n < N) t[ty + i][tx] = S[(long)k * srcLd + n];
    }
    __syncthreads();
#pragma unroll
    for (int i = 0; i < 32; i += 8) {
        int n = n0 + ty + i, k = k0 + tx;
        if (n < N && k < K) D[(long)n * dstLd + k] = __float2bfloat16(t[tx][ty + i]);
    }
}

__global__ void cvt_f2b(const float* __restrict__ s, bf16* __restrict__ d, int n) {
    int i = blockIdx.x * 256 + threadIdx.x;
    if (i < n) d[i] = __float2bfloat16(s[i]);
}

__global__ void pack_qkv_bias(const float* __restrict__ bq, const float* __restrict__ bk,
                              const float* __restrict__ bv, float* __restrict__ qb) {
    int i = blockIdx.x * 256 + threadIdx.x;   // 12*2304
    int l = i / 2304, n = i % 2304;
    float v = (n < 768) ? bq[l * 768 + n]
            : (n < 1536) ? bk[l * 768 + n - 768]
                         : bv[l * 768 + n - 1536];
    qb[i] = v;
}

// ---------------------------------------------------------------------------
// Patch embedding: im2col (fp32 -> bf16), then GEMM, then assemble h (+cls +pos).
// ---------------------------------------------------------------------------
__global__ __launch_bounds__(256) void im2col_k(const float* __restrict__ x, bf16* __restrict__ out) {
    const int row = blockIdx.x;                 // b*196 + gi*14 + gj
    const int b = row / 196, r = row % 196, gi = r / 14, gj = r % 14;
    const float* xb = x + (long)b * 3 * 224 * 224;
    bf16* o = out + (long)row * 768;
    const int tid = threadIdx.x;
#pragma unroll
    for (int i = 0; i < 3; i++) {
        int col = tid + (i << 8);
        int c = col >> 8, rem = col & 255, p = rem >> 4, q = rem & 15;
        o[col] = __float2bfloat16(xb[((long)c * 224 + gi * 16 + p) * 224 + gj * 16 + q]);
    }
}

__global__ __launch_bounds__(256) void assemble_k(const float* __restrict__ hp,
                                                  const float* __restrict__ cls,
                                                  const float* __restrict__ pos,
                                                  float* __restrict__ h) {
    const int row = blockIdx.x;                 // b*197 + t
    const int b = row / 197, t = row % 197;
    float* o = h + (long)row * 768;
    const float* p = pos + (long)t * 768;
    const int tid = threadIdx.x;
#pragma unroll
    for (int i = 0; i < 3; i++) {
        int c = tid + (i << 8);
        float v = (t == 0) ? cls[c] : hp[((long)(b * 196 + t - 1)) * 768 + c];
        o[c] = v + p[c];
    }
}

// ---------------------------------------------------------------------------
// LayerNorm (fp32 in, bf16 out), one row (768) per 256-thread block.
// ---------------------------------------------------------------------------
__global__ __launch_bounds__(256) void layernorm_k(const float* __restrict__ h,
                                                   const float* __restrict__ gamma,
                                                   const float* __restrict__ beta,
                                                   bf16* __restrict__ out) {
    const int row = blockIdx.x;
    const float* x = h + (long)row * 768;
    const int tid = threadIdx.x;
    float v[3], s = 0.f, ss = 0.f;
#pragma unroll
    for (int i = 0; i < 3; i++) { v[i] = x[tid + (i << 8)]; s += v[i]; ss += v[i] * v[i]; }
#pragma unroll
    for (int o = 32; o; o >>= 1) { s += __shfl_xor(s, o); ss += __shfl_xor(ss, o); }
    __shared__ float red[8];
    const int wave = tid >> 6, lane = tid & 63;
    if (lane == 0) { red[wave] = s; red[4 + wave] = ss; }
    __syncthreads();
    if (tid == 0) {
        red[0] = red[0] + red[1] + red[2] + red[3];
        red[4] = red[4] + red[5] + red[6] + red[7];
    }
    __syncthreads();
    const float mu  = red[0] * (1.0f / 768.0f);
    const float var = red[4] * (1.0f / 768.0f) - mu * mu;
    const float inv = rsqrtf(var + 1e-5f);
    bf16* o = out + (long)row * 768;
#pragma unroll
    for (int i = 0; i < 3; i++) {
        int c = tid + (i << 8);
        o[c] = __float2bfloat16((v[i] - mu) * inv * gamma[c] + beta[c]);
    }
}

// ---------------------------------------------------------------------------
// Per-head V transpose: qkv v-columns -> vT[b,h][d(64)][t(224)], zero-padded t>=197.
// grid (4, 384), block 256 (64x4), LDS 64x65 bf16 tile.
// ---------------------------------------------------------------------------
__global__ __launch_bounds__(256) void transpose_v(const bf16* __restrict__ qkv,
                                                   bf16* __restrict__ vT) {
    __shared__ bf16 t[64][65];
    const int t0 = blockIdx.x << 6;
    const int bz = blockIdx.y;             // b*12 + h
    const int b = bz / 12, hh = bz % 12;
    const int tx = threadIdx.x & 63, ty = threadIdx.x >> 6;
#pragma unroll
    for (int i = 0; i < 64; i += 4) {
        int tt = t0 + ty + i;
        bf16 v = __float2bfloat16(0.0f);
        if (tt < 197) v = qkv[((long)(b * 197 + tt)) * 2304 + 1536 + hh * 64 + tx];
        t[ty + i][tx] = v;
    }
    __syncthreads();
    bf16* d = vT + (long)bz * 14336;       // 64 * 224
#pragma unroll
    for (int i = 0; i < 64; i += 4) {
        int tt = t0 + tx;
        if (tt < 224) d[(long)(ty + i) * 224 + tt] = t[tx][ty + i];
    }
}

// ---------------------------------------------------------------------------
// In-place row softmax over bf16 scores [row][224], valid cols 0..196, pads zeroed.
// One wave per row; grid 18912 x block 256 = 75648 rows exactly.
// ---------------------------------------------------------------------------
__global__ __launch_bounds__(256) void softmax_k(bf16* __restrict__ sc) {
    const int row = blockIdx.x * 4 + (threadIdx.x >> 6);
    const int lane = threadIdx.x & 63;
    bf16* s = sc + (long)row * 224;
    float v0 = __bfloat162float(s[lane]);
    float v1 = __bfloat162float(s[64 + lane]);
    float v2 = __bfloat162float(s[128 + lane]);
    float v3 = (192 + lane < 197) ? __bfloat162float(s[192 + lane]) : -1e30f;
    float m = fmaxf(fmaxf(v0, v1), fmaxf(v2, v3));
#pragma unroll
    for (int o = 32; o; o >>= 1) m = fmaxf(m, __shfl_xor(m, o));
    float e0 = __expf(v0 - m), e1 = __expf(v1 - m), e2 = __expf(v2 - m);
    float e3 = (192 + lane < 197) ? __expf(v3 - m) : 0.0f;
    float t = e0 + e1 + e2 + e3;
#pragma unroll
    for (int o = 32; o; o >>= 1) t += __shfl_xor(t, o);
    const float inv = 1.0f / t;
    s[lane]        = __float2bfloat16(e0 * inv);
    s[64 + lane]   = __float2bfloat16(e1 * inv);
    s[128 + lane]  = __float2bfloat16(e2 * inv);
    if (192 + lane < 224) s[192 + lane] = __float2bfloat16(e3 * inv);  // zeros for 197..223
}

__global__ __launch_bounds__(256) void extract_cls(const float* __restrict__ h,
                                                   bf16* __restrict__ hcls) {
    const int b = blockIdx.x, tid = threadIdx.x;
#pragma unroll
    for (int i = 0; i < 3; i++) {
        int c = tid + (i << 8);
        hcls[(long)b * 768 + c] = __float2bfloat16(h[(long)b * 197 * 768 + c]);
    }
}

// ---------------------------------------------------------------------------
extern "C" void kernel_launch(void* const* d_in, const int* in_sizes, int n_in,
                              void* d_out, int out_size, void* d_ws, size_t ws_size,
                              hipStream_t stream)
{
    (void)in_sizes; (void)n_in; (void)out_size; (void)ws_size;
    const float* x      = (const float*)d_in[0];
    const float* conv_w = (const float*)d_in[1];
    const float* conv_b = (const float*)d_in[2];
    const float* cls    = (const float*)d_in[3];
    const float* pos    = (const float*)d_in[4];
    const float* ln1_s  = (const float*)d_in[5];
    const float* ln1_b  = (const float*)d_in[6];
    const float* wq     = (const float*)d_in[7];
    const float* bq     = (const float*)d_in[8];
    const float* wk     = (const float*)d_in[9];
    const float* bk     = (const float*)d_in[10];
    const float* wv     = (const float*)d_in[11];
    const float* bv     = (const float*)d_in[12];
    const float* wo     = (const float*)d_in[13];
    const float* bo     = (const float*)d_in[14];
    const float* ln2_s  = (const float*)d_in[15];
    const float* ln2_b  = (const float*)d_in[16];
    const float* w1     = (const float*)d_in[17];
    const float* b1     = (const float*)d_in[18];
    const float* w2     = (const float*)d_in[19];
    const float* b2     = (const float*)d_in[20];
    const float* head_w = (const float*)d_in[21];
    const float* head_b = (const float*)d_in[22];
    float* out = (float*)d_out;

    // ---- workspace carve-up (~270 MiB) ----
    char* ws = (char*)d_ws;
    size_t off = 0;
    auto take = [&](size_t bytes) -> char* {
        char* p = ws + off; off += (bytes + 255) & ~(size_t)255; return p;
    };
    float* h    = (float*)take(6304UL * 768 * 4);
    bf16*  hn   = (bf16*) take(6304UL * 768 * 2);
    bf16*  qkv  = (bf16*) take(6304UL * 2304 * 2);
    bf16*  att  = (bf16*) take(6304UL * 768 * 2);
    bf16*  Wqkv = (bf16*) take(12UL * 2304 * 768 * 2);
    bf16*  Wo   = (bf16*) take(12UL * 768 * 768 * 2);
    bf16*  W1   = (bf16*) take(12UL * 768 * 3072 * 2);
    bf16*  W2   = (bf16*) take(12UL * 768 * 3072 * 2);
    bf16*  Wp   = (bf16*) take(589824UL * 2);
    bf16*  Wh   = (bf16*) take(768000UL * 2);
    float* qb   = (float*)take(27648UL * 4);
    bf16*  hcls = (bf16*) take(24576UL * 2);
    char*  scr  = take(46UL * 1024 * 1024);   // union: attention scratch / inter / patch
    bf16*  scores = (bf16*)scr;                                 // 384 x 197 x 224
    bf16*  vT     = (bf16*)(scr + 384UL * 197 * 224 * 2);       // 384 x 64 x 224
    bf16*  inter  = (bf16*)scr;                                 // 6304 x 3072 (MLP phase)
    bf16*  Apatch = (bf16*)scr;                                 // 6272 x 768 (patch phase)
    float* hpatch = (float*)(scr + ((6272UL * 768 * 2 + 255) & ~(size_t)255));

    // ---- weight repack (every launch; ws is re-poisoned each call) ----
    cvt_f2b<<<2304, 256, 0, stream>>>(conv_w, Wp, 589824);
    transpose_cvt<<<dim3(2, 24, 144), 256, 0, stream>>>(wq, Wqkv,           768, 64, 64, 768, 12, 49152, 589824, 49152, 1769472);
    transpose_cvt<<<dim3(2, 24, 144), 256, 0, stream>>>(wk, Wqkv + 589824,  768, 64, 64, 768, 12, 49152, 589824, 49152, 1769472);
    transpose_cvt<<<dim3(2, 24, 144), 256, 0, stream>>>(wv, Wqkv + 1179648, 768, 64, 64, 768, 12, 49152, 589824, 49152, 1769472);
    transpose_cvt<<<dim3(24, 24, 12), 256, 0, stream>>>(wo, Wo, 768, 768, 768, 768, 12, 589824, 0, 589824, 0);
    transpose_cvt<<<dim3(96, 24, 12), 256, 0, stream>>>(w1, W1, 768, 3072, 3072, 768, 12, 2359296, 0, 2359296, 0);
    transpose_cvt<<<dim3(24, 96, 12), 256, 0, stream>>>(w2, W2, 3072, 768, 768, 3072, 12, 2359296, 0, 2359296, 0);
    transpose_cvt<<<dim3(32, 24, 1), 256, 0, stream>>>(head_w, Wh, 768, 1000, 1000, 768, 1, 0, 0, 0, 0);
    pack_qkv_bias<<<108, 256, 0, stream>>>(bq, bk, bv, qb);

    // ---- patch embedding ----
    im2col_k<<<6272, 256, 0, stream>>>(x, Apatch);
    gemm_nt<0, 0, 0><<<dim3(6, 49, 1), 512, 0, stream>>>(
        Apatch, Wp, hpatch, nullptr, conv_b, 1.0f,
        6272, 768, 768, 768, 768, 768, 1, 0, 0, 0, 0, 0, 0);
    assemble_k<<<6304, 256, 0, stream>>>(hpatch, cls, pos, h);

    // ---- transformer layers ----
    for (int l = 0; l < 12; ++l) {
        layernorm_k<<<6304, 256, 0, stream>>>(h, ln1_s + l * 768, ln1_b + l * 768, hn);
        gemm_nt<1, 0, 0><<<dim3(18, 50, 1), 512, 0, stream>>>(
            hn, Wqkv + (size_t)l * 1769472, qkv, nullptr, qb + l * 2304, 1.0f,
            6304, 2304, 768, 768, 768, 2304, 1, 0, 0, 0, 0, 0, 0);
        transpose_v<<<dim3(4, 384), 256, 0, stream>>>(qkv, vT);
        // scores = (Q K^T) / 8, batched over (b,h): A=q cols, B=k cols of qkv
        gemm_nt<1, 0, 0><<<dim3(2, 2, 384), 512, 0, stream>>>(
            qkv, qkv + 768, scores, nullptr, nullptr, 0.125f,
            197, 197, 64, 2304, 2304, 224,
            12, 64, 197L * 2304, 64, 197L * 2304, 44128, 529536);
        softmax_k<<<18912, 256, 0, stream>>>(scores);
        // att = P V, batched; C written into att[b,s,h*64+d]
        gemm_nt<1, 0, 0><<<dim3(1, 2, 384), 512, 0, stream>>>(
            scores, vT, att, nullptr, nullptr, 1.0f,
            197, 64, 224, 224, 224, 768,
            12, 44128, 529536, 14336, 172032, 64, 151296);
        // h += att @ Wo + bo
        gemm_nt<0, 0, 1><<<dim3(6, 50, 1), 512, 0, stream>>>(
            att, Wo + (size_t)l * 589824, h, h, bo + l * 768, 1.0f,
            6304, 768, 768, 768, 768, 768, 1, 0, 0, 0, 0, 0, 0);
        layernorm_k<<<6304, 256, 0, stream>>>(h, ln2_s + l * 768, ln2_b + l * 768, hn);
        gemm_nt<1, 1, 0><<<dim3(24, 50, 1), 512, 0, stream>>>(
            hn, W1 + (size_t)l * 2359296, inter, nullptr, b1 + l * 3072, 1.0f,
            6304, 3072, 768, 768, 768, 3072, 1, 0, 0, 0, 0, 0, 0);
        gemm_nt<0, 0, 1><<<dim3(6, 50, 1), 512, 0, stream>>>(
            inter, W2 + (size_t)l * 2359296, h, h, b2 + l * 768, 1.0f,
            6304, 768, 3072, 3072, 3072, 768, 1, 0, 0, 0, 0, 0, 0);
    }

    // ---- classifier head on CLS token (no final LN in reference) ----
    extract_cls<<<32, 256, 0, stream>>>(h, hcls);
    gemm_nt<0, 0, 0><<<dim3(8, 1, 1), 512, 0, stream>>>(
        hcls, Wh, out, nullptr, head_b, 1.0f,
        32, 1000, 768, 768, 768, 1000, 1, 0, 0, 0, 0, 0, 0);
}

// Round 4
// 3793.418 us; speedup vs baseline: 1.1144x; 1.1144x over previous
//
#include <hip/hip_runtime.h>
#include <hip/hip_bf16.h>
#include <math.h>

// ViT-B/16 forward, B=32. All heavy matmuls via bf16 MFMA 16x16x32 (fp32 accum).
// R6: BK=64 K-steps for the big GEMMs (half the barrier/vmcnt/stage overhead per
//     K -- R5 showed the stall is per-phase overhead, not DMA latency) with a
//     both-sides XOR bank-conflict swizzle (LDS stays DMA-linear; global source
//     segs pre-permuted, reads apply the same involution). Attention GEMMs
//     (K=64/224) keep the proven BK=32 R4 path via template. 2-buffer loop with
//     compile-time buffer indices (R5's runtime-indexed 4-buffer VALU cost
//     reverted). 8-wave 128x128 tile, XCD swizzle kept.

using bf16 = __hip_bfloat16;
typedef __attribute__((ext_vector_type(8))) short short8;   // 8 x bf16 MFMA operand
typedef __attribute__((ext_vector_type(4))) float floatx4;  // MFMA accumulator

__device__ __forceinline__ void async_copy16(const bf16* g, bf16* l) {
    __builtin_amdgcn_global_load_lds(
        (const __attribute__((address_space(1))) void*)g,
        (__attribute__((address_space(3))) void*)l, 16, 0, 0);
}

// Raw barrier without the compiler's vmcnt(0)+lgkmcnt(0) drain.
__device__ __forceinline__ void wave_sync_vm0() {
    asm volatile("s_waitcnt vmcnt(0)" ::: "memory");
    __builtin_amdgcn_s_barrier();
    asm volatile("" ::: "memory");
}

// ---------------------------------------------------------------------------
// Generic NT GEMM: C[m,n] = epi( scale * sum_k A[m,k]*B[n,k] + bias[n] (+resid) )
// A bf16 [lda], B bf16 [ldb] (row n holds B^T row = weights [N][K]).
// 128x128 tile, 512 threads = 8 waves in a 4x2 grid; each wave owns a 32x64
// output sub-tile = 2x4 frags of 16x16x32 MFMA.
// BK=32 path (attention GEMMs): exact R4 structure. 8 chunks of 16 rows x 64B;
//   wave w stages chunk w of A and B (2 loads). Unswizzled reads (4-way max).
// BK=64 path (big GEMMs): tile rows are 128B (8 x 16B slots). DMA writes
//   linearly, so the bank swizzle is applied on BOTH other sides (rule #21):
//   lane i fetches global seg (i&7)^((i>>3)&7)  ->  LDS slot j' holds logical
//   seg j'^(row&7); reads use byte = row*128 + ((j ^ (row&7))<<4). Read banks:
//   8 groups x 2 lanes = 2-way = free. 16 chunks of 8 rows; wave w stages
//   chunks {2w,2w+1} of A and B (4 loads).
// Double-buffered LDS; per phase: [vmcnt(0); s_barrier] -> cur buffer landed
// everywhere & other buffer fully consumed; stage(next); ds_read cur + MFMA.
// Two-level batching: bz = bo*batchInner + bi.
// ---------------------------------------------------------------------------
template<int BK, int OUT_BF16, int ACT_GELU, int RESID>
__global__ __launch_bounds__(512, 4) void gemm_nt(
    const bf16* __restrict__ A, const bf16* __restrict__ B, void* __restrict__ Cout,
    const float* __restrict__ resid, const float* __restrict__ bias, float scale,
    int M, int N, int K, int lda, int ldb, int ldc,
    int batchInner, long sAi, long sAo, long sBi, long sBo, long sCi, long sCo)
{
    __shared__ __align__(16) bf16 As[2][128 * BK];
    __shared__ __align__(16) bf16 Bs[2][128 * BK];

    const int bz = blockIdx.z;
    const int bi = bz % batchInner, bo = bz / batchInner;
    const bf16* Ab = A + (long)bi * sAi + (long)bo * sAo;
    const bf16* Bb = B + (long)bi * sBi + (long)bo * sBo;
    const long coff = (long)bi * sCi + (long)bo * sCo;

    // Bijective XCD-aware swizzle (m204): contiguous tile runs per XCD L2.
    const int nbx = gridDim.x;
    const int nwg = nbx * gridDim.y;
    const int orig = blockIdx.y * nbx + blockIdx.x;
    const int q8 = nwg >> 3, r8 = nwg & 7;
    const int xcd = orig & 7, sidx = orig >> 3;
    const int wg = (xcd < r8 ? xcd * (q8 + 1) : r8 * (q8 + 1) + (xcd - r8) * q8) + sidx;
    const int m0 = (wg / nbx) << 7;
    const int n0 = (wg % nbx) << 7;

    const int tid  = threadIdx.x;
    const int lane = tid & 63;
    const int wave = tid >> 6;           // 0..7
    const int wrow = (wave >> 1) << 5;   // 0,32,64,96
    const int wcol = (wave & 1) << 6;    // 0 or 64
    const int quad = lane >> 4;
    const int l16  = lane & 15;

    floatx4 acc[2][4];
#pragma unroll
    for (int i = 0; i < 2; i++)
#pragma unroll
        for (int j = 0; j < 4; j++) acc[i][j] = (floatx4)0.0f;

    // Async-staging global offsets (per-lane).
    long aOff0 = 0, aOff1 = 0, bOff0 = 0, bOff1 = 0;
    if constexpr (BK == 32) {
        const int rIn = lane >> 2;            // row within 16-row chunk
        const int seg = (lane & 3) << 3;      // element offset 0,8,16,24
        const int rA = wave * 16 + rIn;
        aOff0 = (long)min(m0 + rA, M - 1) * lda + seg;
        bOff0 = (long)min(n0 + rA, N - 1) * ldb + seg;
    } else {
        const int rIn = lane >> 3;            // row within 8-row chunk
        const int seg = ((lane & 7) ^ (rIn & 7)) << 3;   // swizzled seg (involution)
        const int rA0 = wave * 16 + rIn, rA1 = wave * 16 + 8 + rIn;
        aOff0 = (long)min(m0 + rA0, M - 1) * lda + seg;
        aOff1 = (long)min(m0 + rA1, M - 1) * lda + seg;
        bOff0 = (long)min(n0 + rA0, N - 1) * ldb + seg;
        bOff1 = (long)min(n0 + rA1, N - 1) * ldb + seg;
    }

    auto stage = [&](int buf, int kt) {
        const long kb = (long)kt * BK;
        if constexpr (BK == 32) {
            async_copy16(Ab + aOff0 + kb, &As[buf][wave * 512]);
            async_copy16(Bb + bOff0 + kb, &Bs[buf][wave * 512]);
        } else {
            async_copy16(Ab + aOff0 + kb, &As[buf][wave * 1024]);
            async_copy16(Ab + aOff1 + kb, &As[buf][wave * 1024 + 512]);
            async_copy16(Bb + bOff0 + kb, &Bs[buf][wave * 1024]);
            async_copy16(Bb + bOff1 + kb, &Bs[buf][wave * 1024 + 512]);
        }
    };

    auto compute = [&](const bf16* __restrict__ Asb, const bf16* __restrict__ Bsb) {
        if constexpr (BK == 32) {
            short8 af[2], bfr[4];
#pragma unroll
            for (int i = 0; i < 2; i++)
                af[i]  = *(const short8*)(&Asb[(wrow + i * 16 + l16) * 32 + quad * 8]);
#pragma unroll
            for (int j = 0; j < 4; j++)
                bfr[j] = *(const short8*)(&Bsb[(wcol + j * 16 + l16) * 32 + quad * 8]);
#pragma unroll
            for (int i = 0; i < 2; i++)
#pragma unroll
                for (int j = 0; j < 4; j++)
                    acc[i][j] = __builtin_amdgcn_mfma_f32_16x16x32_bf16(
                        af[i], bfr[j], acc[i][j], 0, 0, 0);
        } else {
#pragma unroll
            for (int s = 0; s < 2; ++s) {
                short8 af[2], bfr[4];
#pragma unroll
                for (int i = 0; i < 2; i++) {
                    const int R = wrow + i * 16 + l16;
                    af[i] = *(const short8*)(
                        &Asb[R * 64 + ((((s << 2) | quad) ^ (R & 7)) << 3)]);
                }
#pragma unroll
                for (int j = 0; j < 4; j++) {
                    const int R = wcol + j * 16 + l16;
                    bfr[j] = *(const short8*)(
                        &Bsb[R * 64 + ((((s << 2) | quad) ^ (R & 7)) << 3)]);
                }
#pragma unroll
                for (int i = 0; i < 2; i++)
#pragma unroll
                    for (int j = 0; j < 4; j++)
                        acc[i][j] = __builtin_amdgcn_mfma_f32_16x16x32_bf16(
                            af[i], bfr[j], acc[i][j], 0, 0, 0);
            }
        }
    };

    const int kTiles = K / BK;   // >= 1
    stage(0, 0);
    for (int kt = 0; kt < kTiles; kt += 2) {
        wave_sync_vm0();                       // buf0 ready; buf1 fully consumed
        if (kt + 1 < kTiles) stage(1, kt + 1); // async, hides under compute
        compute(As[0], Bs[0]);
        if (kt + 1 < kTiles) {
            wave_sync_vm0();                   // buf1 ready; buf0 fully consumed
            if (kt + 2 < kTiles) stage(0, kt + 2);
            compute(As[1], Bs[1]);
        }
    }

    // Epilogue. C/D frag: col = lane&15, row = quad*4 + r.
#pragma unroll
    for (int i = 0; i < 2; i++) {
        const int rbase = m0 + wrow + i * 16 + quad * 4;
#pragma unroll
        for (int j = 0; j < 4; j++) {
            const int col = n0 + wcol + j * 16 + l16;
            if (col >= N) continue;
            const float bval = bias ? bias[col] : 0.0f;
#pragma unroll
            for (int r = 0; r < 4; r++) {
                const int row = rbase + r;
                if (row >= M) continue;
                const long idx = coff + (long)row * ldc + col;
                float v = acc[i][j][r] * scale + bval;
                if (RESID)    v += resid[idx];
                if (ACT_GELU) v = 0.5f * v * (1.0f + erff(v * 0.70710678118654752f));
                if (OUT_BF16) ((bf16*)Cout)[idx] = __float2bfloat16(v);
                else          ((float*)Cout)[idx] = v;
            }
        }
    }
}

// ---------------------------------------------------------------------------
// Weight repack: fp32 src [K][N] (row k) -> bf16 dst [N][K] (row n). 32x32 LDS tiles.
// ---------------------------------------------------------------------------
__global__ __launch_bounds__(256) void transpose_cvt(
    const float* __restrict__ src, bf16* __restrict__ dst, int K, int N,
    int srcLd, int dstLd, int batchInner, long sSi, long sSo, long sDi, long sDo)
{
    __shared__ float t[32][33];
    const int bz = blockIdx.z;
    const int bi = bz % batchInner, bo = bz / batchInner;
    const float* S = src + (long)bi * sSi + (long)bo * sSo;
    bf16* D = dst + (long)bi * sDi + (long)bo * sDo;
    const int k0 = blockIdx.y << 5, n0 = blockIdx.x << 5;
    const int tx = threadIdx.x & 31, ty = threadIdx.x >> 5;   // 32 x 8
#pragma unroll
    for (int i = 0; i < 32; i += 8) {
        int k = k0 + ty + i, n = n0 + tx;
        if (k < K && n < N) t[ty + i][tx] = S[(long)k * srcLd + n];
    }
    __syncthreads();
#pragma unroll
    for (int i = 0; i < 32; i += 8) {
        int n = n0 + ty + i, k = k0 + tx;
        if (n < N && k < K) D[(long)n * dstLd + k] = __float2bfloat16(t[tx][ty + i]);
    }
}

__global__ void cvt_f2b(const float* __restrict__ s, bf16* __restrict__ d, int n) {
    int i = blockIdx.x * 256 + threadIdx.x;
    if (i < n) d[i] = __float2bfloat16(s[i]);
}

__global__ void pack_qkv_bias(const float* __restrict__ bq, const float* __restrict__ bk,
                              const float* __restrict__ bv, float* __restrict__ qb) {
    int i = blockIdx.x * 256 + threadIdx.x;   // 12*2304
    int l = i / 2304, n = i % 2304;
    float v = (n < 768) ? bq[l * 768 + n]
            : (n < 1536) ? bk[l * 768 + n - 768]
                         : bv[l * 768 + n - 1536];
    qb[i] = v;
}

// ---------------------------------------------------------------------------
// Patch embedding: im2col (fp32 -> bf16), then GEMM, then assemble h (+cls +pos).
// ---------------------------------------------------------------------------
__global__ __launch_bounds__(256) void im2col_k(const float* __restrict__ x, bf16* __restrict__ out) {
    const int row = blockIdx.x;                 // b*196 + gi*14 + gj
    const int b = row / 196, r = row % 196, gi = r / 14, gj = r % 14;
    const float* xb = x + (long)b * 3 * 224 * 224;
    bf16* o = out + (long)row * 768;
    const int tid = threadIdx.x;
#pragma unroll
    for (int i = 0; i < 3; i++) {
        int col = tid + (i << 8);
        int c = col >> 8, rem = col & 255, p = rem >> 4, q = rem & 15;
        o[col] = __float2bfloat16(xb[((long)c * 224 + gi * 16 + p) * 224 + gj * 16 + q]);
    }
}

__global__ __launch_bounds__(256) void assemble_k(const float* __restrict__ hp,
                                                  const float* __restrict__ cls,
                                                  const float* __restrict__ pos,
                                                  float* __restrict__ h) {
    const int row = blockIdx.x;                 // b*197 + t
    const int b = row / 197, t = row % 197;
    float* o = h + (long)row * 768;
    const float* p = pos + (long)t * 768;
    const int tid = threadIdx.x;
#pragma unroll
    for (int i = 0; i < 3; i++) {
        int c = tid + (i << 8);
        float v = (t == 0) ? cls[c] : hp[((long)(b * 196 + t - 1)) * 768 + c];
        o[c] = v + p[c];
    }
}

// ---------------------------------------------------------------------------
// LayerNorm (fp32 in, bf16 out), one row (768) per 256-thread block.
// ---------------------------------------------------------------------------
__global__ __launch_bounds__(256) void layernorm_k(const float* __restrict__ h,
                                                   const float* __restrict__ gamma,
                                                   const float* __restrict__ beta,
                                                   bf16* __restrict__ out) {
    const int row = blockIdx.x;
    const float* x = h + (long)row * 768;
    const int tid = threadIdx.x;
    float v[3], s = 0.f, ss = 0.f;
#pragma unroll
    for (int i = 0; i < 3; i++) { v[i] = x[tid + (i << 8)]; s += v[i]; ss += v[i] * v[i]; }
#pragma unroll
    for (int o = 32; o; o >>= 1) { s += __shfl_xor(s, o); ss += __shfl_xor(ss, o); }
    __shared__ float red[8];
    const int wave = tid >> 6, lane = tid & 63;
    if (lane == 0) { red[wave] = s; red[4 + wave] = ss; }
    __syncthreads();
    if (tid == 0) {
        red[0] = red[0] + red[1] + red[2] + red[3];
        red[4] = red[4] + red[5] + red[6] + red[7];
    }
    __syncthreads();
    const float mu  = red[0] * (1.0f / 768.0f);
    const float var = red[4] * (1.0f / 768.0f) - mu * mu;
    const float inv = rsqrtf(var + 1e-5f);
    bf16* o = out + (long)row * 768;
#pragma unroll
    for (int i = 0; i < 3; i++) {
        int c = tid + (i << 8);
        o[c] = __float2bfloat16((v[i] - mu) * inv * gamma[c] + beta[c]);
    }
}

// ---------------------------------------------------------------------------
// Per-head V transpose: qkv v-columns -> vT[b,h][d(64)][t(224)], zero-padded t>=197.
// grid (4, 384), block 256 (64x4), LDS 64x65 bf16 tile.
// ---------------------------------------------------------------------------
__global__ __launch_bounds__(256) void transpose_v(const bf16* __restrict__ qkv,
                                                   bf16* __restrict__ vT) {
    __shared__ bf16 t[64][65];
    const int t0 = blockIdx.x << 6;
    const int bz = blockIdx.y;             // b*12 + h
    const int b = bz / 12, hh = bz % 12;
    const int tx = threadIdx.x & 63, ty = threadIdx.x >> 6;
#pragma unroll
    for (int i = 0; i < 64; i += 4) {
        int tt = t0 + ty + i;
        bf16 v = __float2bfloat16(0.0f);
        if (tt < 197) v = qkv[((long)(b * 197 + tt)) * 2304 + 1536 + hh * 64 + tx];
        t[ty + i][tx] = v;
    }
    __syncthreads();
    bf16* d = vT + (long)bz * 14336;       // 64 * 224
#pragma unroll
    for (int i = 0; i < 64; i += 4) {
        int tt = t0 + tx;
        if (tt < 224) d[(long)(ty + i) * 224 + tt] = t[tx][ty + i];
    }
}

// ---------------------------------------------------------------------------
// In-place row softmax over bf16 scores [row][224], valid cols 0..196, pads zeroed.
// One wave per row; grid 18912 x block 256 = 75648 rows exactly.
// ---------------------------------------------------------------------------
__global__ __launch_bounds__(256) void softmax_k(bf16* __restrict__ sc) {
    const int row = blockIdx.x * 4 + (threadIdx.x >> 6);
    const int lane = threadIdx.x & 63;
    bf16* s = sc + (long)row * 224;
    float v0 = __bfloat162float(s[lane]);
    float v1 = __bfloat162float(s[64 + lane]);
    float v2 = __bfloat162float(s[128 + lane]);
    float v3 = (192 + lane < 197) ? __bfloat162float(s[192 + lane]) : -1e30f;
    float m = fmaxf(fmaxf(v0, v1), fmaxf(v2, v3));
#pragma unroll
    for (int o = 32; o; o >>= 1) m = fmaxf(m, __shfl_xor(m, o));
    float e0 = __expf(v0 - m), e1 = __expf(v1 - m), e2 = __expf(v2 - m);
    float e3 = (192 + lane < 197) ? __expf(v3 - m) : 0.0f;
    float t = e0 + e1 + e2 + e3;
#pragma unroll
    for (int o = 32; o; o >>= 1) t += __shfl_xor(t, o);
    const float inv = 1.0f / t;
    s[lane]        = __float2bfloat16(e0 * inv);
    s[64 + lane]   = __float2bfloat16(e1 * inv);
    s[128 + lane]  = __float2bfloat16(e2 * inv);
    if (192 + lane < 224) s[192 + lane] = __float2bfloat16(e3 * inv);  // zeros for 197..223
}

__global__ __launch_bounds__(256) void extract_cls(const float* __restrict__ h,
                                                   bf16* __restrict__ hcls) {
    const int b = blockIdx.x, tid = threadIdx.x;
#pragma unroll
    for (int i = 0; i < 3; i++) {
        int c = tid + (i << 8);
        hcls[(long)b * 768 + c] = __float2bfloat16(h[(long)b * 197 * 768 + c]);
    }
}

// ---------------------------------------------------------------------------
extern "C" void kernel_launch(void* const* d_in, const int* in_sizes, int n_in,
                              void* d_out, int out_size, void* d_ws, size_t ws_size,
                              hipStream_t stream)
{
    (void)in_sizes; (void)n_in; (void)out_size; (void)ws_size;
    const float* x      = (const float*)d_in[0];
    const float* conv_w = (const float*)d_in[1];
    const float* conv_b = (const float*)d_in[2];
    const float* cls    = (const float*)d_in[3];
    const float* pos    = (const float*)d_in[4];
    const float* ln1_s  = (const float*)d_in[5];
    const float* ln1_b  = (const float*)d_in[6];
    const float* wq     = (const float*)d_in[7];
    const float* bq     = (const float*)d_in[8];
    const float* wk     = (const float*)d_in[9];
    const float* bk     = (const float*)d_in[10];
    const float* wv     = (const float*)d_in[11];
    const float* bv     = (const float*)d_in[12];
    const float* wo     = (const float*)d_in[13];
    const float* bo     = (const float*)d_in[14];
    const float* ln2_s  = (const float*)d_in[15];
    const float* ln2_b  = (const float*)d_in[16];
    const float* w1     = (const float*)d_in[17];
    const float* b1     = (const float*)d_in[18];
    const float* w2     = (const float*)d_in[19];
    const float* b2     = (const float*)d_in[20];
    const float* head_w = (const float*)d_in[21];
    const float* head_b = (const float*)d_in[22];
    float* out = (float*)d_out;

    // ---- workspace carve-up (~270 MiB) ----
    char* ws = (char*)d_ws;
    size_t off = 0;
    auto take = [&](size_t bytes) -> char* {
        char* p = ws + off; off += (bytes + 255) & ~(size_t)255; return p;
    };
    float* h    = (float*)take(6304UL * 768 * 4);
    bf16*  hn   = (bf16*) take(6304UL * 768 * 2);
    bf16*  qkv  = (bf16*) take(6304UL * 2304 * 2);
    bf16*  att  = (bf16*) take(6304UL * 768 * 2);
    bf16*  Wqkv = (bf16*) take(12UL * 2304 * 768 * 2);
    bf16*  Wo   = (bf16*) take(12UL * 768 * 768 * 2);
    bf16*  W1   = (bf16*) take(12UL * 768 * 3072 * 2);
    bf16*  W2   = (bf16*) take(12UL * 768 * 3072 * 2);
    bf16*  Wp   = (bf16*) take(589824UL * 2);
    bf16*  Wh   = (bf16*) take(768000UL * 2);
    float* qb   = (float*)take(27648UL * 4);
    bf16*  hcls = (bf16*) take(24576UL * 2);
    char*  scr  = take(46UL * 1024 * 1024);   // union: attention scratch / inter / patch
    bf16*  scores = (bf16*)scr;                                 // 384 x 197 x 224
    bf16*  vT     = (bf16*)(scr + 384UL * 197 * 224 * 2);       // 384 x 64 x 224
    bf16*  inter  = (bf16*)scr;                                 // 6304 x 3072 (MLP phase)
    bf16*  Apatch = (bf16*)scr;                                 // 6272 x 768 (patch phase)
    float* hpatch = (float*)(scr + ((6272UL * 768 * 2 + 255) & ~(size_t)255));

    // ---- weight repack (every launch; ws is re-poisoned each call) ----
    cvt_f2b<<<2304, 256, 0, stream>>>(conv_w, Wp, 589824);
    transpose_cvt<<<dim3(2, 24, 144), 256, 0, stream>>>(wq, Wqkv,           768, 64, 64, 768, 12, 49152, 589824, 49152, 1769472);
    transpose_cvt<<<dim3(2, 24, 144), 256, 0, stream>>>(wk, Wqkv + 589824,  768, 64, 64, 768, 12, 49152, 589824, 49152, 1769472);
    transpose_cvt<<<dim3(2, 24, 144), 256, 0, stream>>>(wv, Wqkv + 1179648, 768, 64, 64, 768, 12, 49152, 589824, 49152, 1769472);
    transpose_cvt<<<dim3(24, 24, 12), 256, 0, stream>>>(wo, Wo, 768, 768, 768, 768, 12, 589824, 0, 589824, 0);
    transpose_cvt<<<dim3(96, 24, 12), 256, 0, stream>>>(w1, W1, 768, 3072, 3072, 768, 12, 2359296, 0, 2359296, 0);
    transpose_cvt<<<dim3(24, 96, 12), 256, 0, stream>>>(w2, W2, 3072, 768, 768, 3072, 12, 2359296, 0, 2359296, 0);
    transpose_cvt<<<dim3(32, 24, 1), 256, 0, stream>>>(head_w, Wh, 768, 1000, 1000, 768, 1, 0, 0, 0, 0);
    pack_qkv_bias<<<108, 256, 0, stream>>>(bq, bk, bv, qb);

    // ---- patch embedding ----
    im2col_k<<<6272, 256, 0, stream>>>(x, Apatch);
    gemm_nt<64, 0, 0, 0><<<dim3(6, 49, 1), 512, 0, stream>>>(
        Apatch, Wp, hpatch, nullptr, conv_b, 1.0f,
        6272, 768, 768, 768, 768, 768, 1, 0, 0, 0, 0, 0, 0);
    assemble_k<<<6304, 256, 0, stream>>>(hpatch, cls, pos, h);

    // ---- transformer layers ----
    for (int l = 0; l < 12; ++l) {
        layernorm_k<<<6304, 256, 0, stream>>>(h, ln1_s + l * 768, ln1_b + l * 768, hn);
        gemm_nt<64, 1, 0, 0><<<dim3(18, 50, 1), 512, 0, stream>>>(
            hn, Wqkv + (size_t)l * 1769472, qkv, nullptr, qb + l * 2304, 1.0f,
            6304, 2304, 768, 768, 768, 2304, 1, 0, 0, 0, 0, 0, 0);
        transpose_v<<<dim3(4, 384), 256, 0, stream>>>(qkv, vT);
        // scores = (Q K^T) / 8, batched over (b,h): A=q cols, B=k cols of qkv
        gemm_nt<32, 1, 0, 0><<<dim3(2, 2, 384), 512, 0, stream>>>(
            qkv, qkv + 768, scores, nullptr, nullptr, 0.125f,
            197, 197, 64, 2304, 2304, 224,
            12, 64, 197L * 2304, 64, 197L * 2304, 44128, 529536);
        softmax_k<<<18912, 256, 0, stream>>>(scores);
        // att = P V, batched; C written into att[b,s,h*64+d]
        gemm_nt<32, 1, 0, 0><<<dim3(1, 2, 384), 512, 0, stream>>>(
            scores, vT, att, nullptr, nullptr, 1.0f,
            197, 64, 224, 224, 224, 768,
            12, 44128, 529536, 14336, 172032, 64, 151296);
        // h += att @ Wo + bo
        gemm_nt<64, 0, 0, 1><<<dim3(6, 50, 1), 512, 0, stream>>>(
            att, Wo + (size_t)l * 589824, h, h, bo + l * 768, 1.0f,
            6304, 768, 768, 768, 768, 768, 1, 0, 0, 0, 0, 0, 0);
        layernorm_k<<<6304, 256, 0, stream>>>(h, ln2_s + l * 768, ln2_b + l * 768, hn);
        gemm_nt<64, 1, 1, 0><<<dim3(24, 50, 1), 512, 0, stream>>>(
            hn, W1 + (size_t)l * 2359296, inter, nullptr, b1 + l * 3072, 1.0f,
            6304, 3072, 768, 768, 768, 3072, 1, 0, 0, 0, 0, 0, 0);
        gemm_nt<64, 0, 0, 1><<<dim3(6, 50, 1), 512, 0, stream>>>(
            inter, W2 + (size_t)l * 2359296, h, h, b2 + l * 768, 1.0f,
            6304, 768, 3072, 3072, 3072, 768, 1, 0, 0, 0, 0, 0, 0);
    }

    // ---- classifier head on CLS token (no final LN in reference) ----
    extract_cls<<<32, 256, 0, stream>>>(h, hcls);
    gemm_nt<64, 0, 0, 0><<<dim3(8, 1, 1), 512, 0, stream>>>(
        hcls, Wh, out, nullptr, head_b, 1.0f,
        32, 1000, 768, 768, 768, 1000, 1, 0, 0, 0, 0, 0, 0);
}